// Round 1
// baseline (91.653 us; speedup 1.0000x reference)
//
#include <hip/hip_runtime.h>

// Problem constants
#define G_      52
#define GG_     2704          // G*G
#define CH_     88            // 5+1+C
#define NTOP_   53
#define CTOT_   82
#define PTOT_   259584        // B*A*G*G = 32*3*2704
#define NTGT_   512
#define LDSPAD_ 65            // 64 + 1 pad (65 % 32 == 1 -> conflict-free)

__device__ __forceinline__ float sigf(float v) {
    return 1.0f / (1.0f + __expf(-v));
}

// ws layout (doubles):
//  [0..63]  noobj_all partials (kernel1)
//  [64] box_sum  [65] conf_obj_sum  [66] istop_sum
//  [67] itm_sum  [68] ibm_sum  [69] itm_cnt  [70] ibm_cnt
//  [71] noobj_sub_sum  [72] hit_cnt

__global__ __launch_bounds__(256) void yolo_main(const float* __restrict__ x,
                                                 const float* __restrict__ anchors,
                                                 float* __restrict__ out,
                                                 double* __restrict__ ws) {
    __shared__ float lds[CH_ * LDSPAD_];
    const int tid   = threadIdx.x;
    const int pbase = blockIdx.x * 64;   // 4056 tiles of 64 positions

    const float a0w = anchors[0], a0h = anchors[1];
    const float a1w = anchors[2], a1h = anchors[3];
    const float a2w = anchors[4], a2h = anchors[5];

    float noobj = 0.0f;

    // read + transform: 88 ch x 64 pos = 5632 elems, 22 iters of 256 threads
    for (int i = 0; i < 22; ++i) {
        int idx = i * 256 + tid;
        int c   = idx >> 6;          // wave-uniform
        int pos = idx & 63;
        int p   = pbase + pos;
        int ba  = p / GG_;           // b*3 + a
        int q   = p - ba * GG_;      // gy*G + gx
        float v = x[(ba * CH_ + c) * GG_ + q];
        float tv;
        if (c >= 4) {
            float s = sigf(v);
            tv = s;
            if (c == 4) {
                // all-cells no-obj BCE term: -clip(log1p(-p_conf), -100)
                noobj -= fmaxf(log1pf(-s), -100.0f);
            }
        } else if (c == 0) {
            int gx = q % G_;
            tv = ((float)gx + sigf(v)) * 8.0f;           // stride = 416/52
        } else if (c == 1) {
            int gy = q / G_;
            tv = ((float)gy + sigf(v)) * 8.0f;
        } else {                                          // c==2 or c==3
            int a = ba % 3;
            float anc = (a == 0) ? (c == 2 ? a0w : a0h)
                      : (a == 1) ? (c == 2 ? a1w : a1h)
                                 : (c == 2 ? a2w : a2h);
            tv = anc * __expf(v) * 416.0f;
        }
        lds[c * LDSPAD_ + pos] = tv;
    }

    // c==4 only occurs for i==1, tid<64 -> wave 0 holds all partials
    if (tid < 64) {
        for (int off = 32; off; off >>= 1)
            noobj += __shfl_xor(noobj, off);
        if (tid == 0)
            atomicAdd(&ws[blockIdx.x & 63], (double)noobj);
    }
    __syncthreads();

    // write: 5632 contiguous floats per tile
    const int ob = pbase * CH_;
    for (int i = 0; i < 22; ++i) {
        int idx = i * 256 + tid;
        int pos = idx / CH_;
        int c   = idx - pos * CH_;
        out[ob + idx] = lds[c * LDSPAD_ + pos];
    }
}

__global__ __launch_bounds__(64) void yolo_tgt(const float* __restrict__ x,
                                               const float* __restrict__ tgt,
                                               const float* __restrict__ anchors,
                                               double* __restrict__ ws) {
    const int n = blockIdx.x * 64 + threadIdx.x;   // 8 blocks x 64 = 512

    const float* t = tgt + n * CH_;
    int   bi  = (int)t[0];
    float tcx = t[1] * (float)G_;
    float tcy = t[2] * (float)G_;
    float tw  = t[3], th = t[4], tistop = t[5];
    int   ci  = (int)tcx;
    int   cj  = (int)tcy;
    int   q   = cj * G_ + ci;

    float iou[3];
    int best = 0;
    float best_iou = -1.0f;
    for (int a = 0; a < 3; ++a) {
        float aw = anchors[2 * a], ah = anchors[2 * a + 1];
        float inter = fminf(aw, tw) * fminf(ah, th);
        float uni   = tw * th + aw * ah - inter + 1e-16f;
        iou[a] = inter / uni;
        if (iou[a] > best_iou) { best_iou = iou[a]; best = a; }
    }

    const float* cell = x + (bi * 3 + best) * CH_ * GG_ + q;   // ch stride GG_

    // box MSE (all divided by 512 later)
    float tfx = tcx - floorf(tcx);
    float tfy = tcy - floorf(tcy);
    float twt = logf(tw / anchors[2 * best]     + 1e-16f);
    float tht = logf(th / anchors[2 * best + 1] + 1e-16f);
    float d, box_s = 0.0f;
    d = sigf(cell[0])        - tfx; box_s += d * d;
    d = sigf(cell[GG_])      - tfy; box_s += d * d;
    d = cell[2 * GG_]        - twt; box_s += d * d;
    d = cell[3 * GG_]        - tht; box_s += d * d;

    // conf BCE at obj cell (t=1): -clip(log(p))
    float pc = sigf(cell[4 * GG_]);
    float conf_s = -fmaxf(logf(pc), -100.0f);

    // is_top BCE at obj cell
    float pt = sigf(cell[5 * GG_]);
    float istop_s = -(tistop * fmaxf(logf(pt), -100.0f) +
                      (1.0f - tistop) * fmaxf(log1pf(-pt), -100.0f));

    // class BCE on masked channels
    bool is_top = tistop > 0.5f;
    int  c0 = is_top ? 0 : NTOP_;
    int  c1 = is_top ? NTOP_ : CTOT_;
    float cls_s = 0.0f;
    for (int c = c0; c < c1; ++c) {
        float p  = sigf(cell[(6 + c) * GG_]);
        float tt = t[6 + c];
        cls_s += -(tt * fmaxf(logf(p), -100.0f) +
                   (1.0f - tt) * fmaxf(log1pf(-p), -100.0f));
    }
    float itm_s = is_top ? cls_s : 0.0f;
    float ibm_s = is_top ? 0.0f  : cls_s;
    float itm_c = is_top ? (float)NTOP_ : 0.0f;
    float ibm_c = is_top ? 0.0f : (float)(CTOT_ - NTOP_);

    // hit cells: subtract their all-cells no-obj contribution
    float nsub = 0.0f, hitc = 0.0f;
    for (int a = 0; a < 3; ++a) {
        if (iou[a] > 0.5f || a == best) {
            float p = sigf(x[((bi * 3 + a) * CH_ + 4) * GG_ + q]);
            nsub += -fmaxf(log1pf(-p), -100.0f);
            hitc += 1.0f;
        }
    }

    // wave reduction (block = exactly 1 wave)
    for (int off = 32; off; off >>= 1) {
        box_s   += __shfl_xor(box_s, off);
        conf_s  += __shfl_xor(conf_s, off);
        istop_s += __shfl_xor(istop_s, off);
        itm_s   += __shfl_xor(itm_s, off);
        ibm_s   += __shfl_xor(ibm_s, off);
        itm_c   += __shfl_xor(itm_c, off);
        ibm_c   += __shfl_xor(ibm_c, off);
        nsub    += __shfl_xor(nsub, off);
        hitc    += __shfl_xor(hitc, off);
    }
    if (threadIdx.x == 0) {
        atomicAdd(&ws[64], (double)box_s);
        atomicAdd(&ws[65], (double)conf_s);
        atomicAdd(&ws[66], (double)istop_s);
        atomicAdd(&ws[67], (double)itm_s);
        atomicAdd(&ws[68], (double)ibm_s);
        atomicAdd(&ws[69], (double)itm_c);
        atomicAdd(&ws[70], (double)ibm_c);
        atomicAdd(&ws[71], (double)nsub);
        atomicAdd(&ws[72], (double)hitc);
    }
}

__global__ void yolo_final(const double* __restrict__ ws, float* __restrict__ out) {
    double noobj_all = 0.0;
    for (int i = 0; i < 64; ++i) noobj_all += ws[i];
    double box = ws[64], conf = ws[65], istop = ws[66];
    double itm = ws[67], ibm = ws[68];
    double itmc = ws[69], ibmc = ws[70];
    double nsub = ws[71], hitc = ws[72];

    double nob  = noobj_all - nsub;
    double nobc = (double)PTOT_ - hitc;

    double loss = box / 512.0
                + conf / 512.0
                + 10.0 * ((nobc > 0.0) ? nob / fmax(nobc, 1.0) : 0.0)
                + istop / 512.0
                + ((itmc > 0.0) ? itm / fmax(itmc, 1.0) : 0.0)
                + ((ibmc > 0.0) ? ibm / fmax(ibmc, 1.0) : 0.0);

    out[PTOT_ * CH_] = (float)loss;
}

extern "C" void kernel_launch(void* const* d_in, const int* in_sizes, int n_in,
                              void* d_out, int out_size, void* d_ws, size_t ws_size,
                              hipStream_t stream) {
    const float* x       = (const float*)d_in[0];
    const float* target  = (const float*)d_in[1];
    const float* anchors = (const float*)d_in[2];
    float*  out = (float*)d_out;
    double* ws  = (double*)d_ws;

    // ws is poisoned once and never re-poisoned: zero it ourselves every call.
    hipMemsetAsync(d_ws, 0, 73 * sizeof(double), stream);

    yolo_main <<<dim3(PTOT_ / 64), dim3(256), 0, stream>>>(x, anchors, out, ws);
    yolo_tgt  <<<dim3(NTGT_ / 64), dim3(64),  0, stream>>>(x, target, anchors, ws);
    yolo_final<<<dim3(1),          dim3(1),   0, stream>>>(ws, out);
}

// Round 2
// 55.889 us; speedup vs baseline: 1.6399x; 1.6399x over previous
//
#include <hip/hip_runtime.h>

// Problem constants
#define G_      52
#define GG_     2704          // G*G
#define CH_     88            // 5+1+C
#define NTOP_   53
#define CTOT_   82
#define PTOT_   259584        // B*A*G*G = 32*3*2704
#define NTGT_   512

__device__ __forceinline__ float sigf(float v) {
    return 1.0f / (1.0f + __expf(-v));
}

// Swizzled LDS float index for element (c, pos), logical layout [88][64].
// XOR of c-block bits into pos bits 2..4: b128 ops stay 16B-aligned,
// transpose reads spread across banks.
__device__ __forceinline__ int lidx(int c, int pos) {
    return c * 64 + (pos ^ (((c >> 2) & 7) << 2));
}

// ws layout (doubles):
//  [0..63]    noobj_all partials (yolo_main)
//  [64..71]   s512  (box + conf_obj + istop sums, all /512 later)
//  [72..79]   itm   [80..87] ibm
//  [88..95]   nsub  [96..103] hitc
//  [104..111] itmc  [112..119] ibmc

__global__ __launch_bounds__(256) void yolo_main(const float* __restrict__ x,
                                                 const float* __restrict__ anchors,
                                                 float* __restrict__ out,
                                                 double* __restrict__ ws) {
    __shared__ float lds[CH_ * 64];
    const int tid   = threadIdx.x;
    const int pbase = blockIdx.x * 64;   // 4056 tiles of 64 positions

    float noobj = 0.0f;

    // read + transform: 88 ch x 64 pos, float4 per lane (4 consecutive pos)
    #pragma unroll
    for (int i = 0; i < 6; ++i) {
        int c = i * 16 + (tid >> 4);       // 16 lanes per channel
        if (c < CH_) {
            int pos = (tid & 15) * 4;
            int p   = pbase + pos;
            int ba  = p / GG_;             // GG%4==0 -> same ba for all 4
            int q   = p - ba * GG_;        // q multiple of 4
            float4 v = *(const float4*)(x + (ba * CH_ + c) * GG_ + q);
            float4 tv;
            float* vv = (float*)&v;
            float* tt = (float*)&tv;
            if (c >= 4) {
                #pragma unroll
                for (int k = 0; k < 4; ++k) tt[k] = sigf(vv[k]);
                if (c == 4) {
                    #pragma unroll
                    for (int k = 0; k < 4; ++k)
                        noobj -= fmaxf(log1pf(-tt[k]), -100.0f);
                }
            } else if (c == 0) {
                int gx = q % G_;           // q mult of 4, 52%4==0 -> gx+3<=51
                #pragma unroll
                for (int k = 0; k < 4; ++k)
                    tt[k] = ((float)(gx + k) + sigf(vv[k])) * 8.0f;
            } else if (c == 1) {
                int gy = q / G_;           // constant across the 4
                #pragma unroll
                for (int k = 0; k < 4; ++k)
                    tt[k] = ((float)gy + sigf(vv[k])) * 8.0f;
            } else {                       // c==2 or c==3
                int a = ba - (ba / 3) * 3;
                float anc = anchors[2 * a + (c - 2)];
                #pragma unroll
                for (int k = 0; k < 4; ++k)
                    tt[k] = anc * __expf(vv[k]) * 416.0f;
            }
            *(float4*)(lds + lidx(c, pos)) = tv;
        }
    }

    // c==4 occurs only for i==0, tid in [64,80) -> wave 1 holds all partials
    if ((tid >> 6) == 1) {
        for (int off = 32; off; off >>= 1)
            noobj += __shfl_xor(noobj, off);
        if (tid == 64)
            atomicAdd(&ws[blockIdx.x & 63], (double)noobj);
    }
    __syncthreads();

    // write: 5632 floats = 1408 float4s per tile, contiguous
    const int ob = pbase * CH_;
    #pragma unroll
    for (int i = 0; i < 6; ++i) {
        int idx = i * 256 + tid;           // float4 index
        if (idx < 1408) {
            int pos = idx / 22;            // f=4*idx; pos=f/88
            int c   = 4 * (idx - pos * 22);// c multiple of 4 -> same swizzle
            float4 o;
            float* oo = (float*)&o;
            #pragma unroll
            for (int k = 0; k < 4; ++k)
                oo[k] = lds[lidx(c + k, pos)];
            *(float4*)(out + ob + idx * 4) = o;
        }
    }
}

// One 64-lane wave per target: class-BCE channels one-per-lane,
// box/conf/istop/noobj-sub terms on lanes 56..63.
__global__ __launch_bounds__(64) void yolo_tgt(const float* __restrict__ x,
                                               const float* __restrict__ tgt,
                                               const float* __restrict__ anchors,
                                               double* __restrict__ ws) {
    const int n    = blockIdx.x;
    const int lane = threadIdx.x;
    const float* t = tgt + n * CH_;

    float a_w[3], a_h[3];
    #pragma unroll
    for (int a = 0; a < 3; ++a) { a_w[a] = anchors[2*a]; a_h[a] = anchors[2*a+1]; }

    int   bi  = (int)t[0];
    float tcx = t[1] * (float)G_;
    float tcy = t[2] * (float)G_;
    float tw  = t[3], th = t[4], tistop = t[5];
    int   ci  = (int)tcx;
    int   cj  = (int)tcy;
    int   q   = cj * G_ + ci;

    float iou[3];
    int best = 0;
    float best_iou = -1.0f;
    #pragma unroll
    for (int a = 0; a < 3; ++a) {
        float inter = fminf(a_w[a], tw) * fminf(a_h[a], th);
        float uni   = tw * th + a_w[a] * a_h[a] - inter + 1e-16f;
        iou[a] = inter / uni;
        if (iou[a] > best_iou) { best_iou = iou[a]; best = a; }
    }

    const float* cell = x + (bi * 3 + best) * CH_ * GG_ + q;  // ch stride GG_
    bool is_top = tistop > 0.5f;
    int  c0 = is_top ? 0 : NTOP_;
    int  nc = is_top ? NTOP_ : (CTOT_ - NTOP_);

    float cls_s = 0.0f, s512 = 0.0f, nsub = 0.0f;
    if (lane < nc) {
        // masked class BCE, one channel per lane
        int c = c0 + lane;
        float p  = sigf(cell[(6 + c) * GG_]);
        float tv = t[6 + c];
        cls_s = -(tv * fmaxf(logf(p), -100.0f) +
                  (1.0f - tv) * fmaxf(log1pf(-p), -100.0f));
    } else if (lane >= 56 && lane < 60) {
        // box MSE components
        int k = lane - 56;
        float v = cell[k * GG_];
        float tv;
        if      (k == 0) tv = tcx - floorf(tcx);
        else if (k == 1) tv = tcy - floorf(tcy);
        else if (k == 2) tv = logf(tw / a_w[best] + 1e-16f);
        else             tv = logf(th / a_h[best] + 1e-16f);
        float d = (k < 2 ? sigf(v) : v) - tv;
        s512 = d * d;
    } else if (lane == 60) {
        // conf BCE (t=1) + is_top BCE at obj cell
        float pc = sigf(cell[4 * GG_]);
        float pt = sigf(cell[5 * GG_]);
        s512 = -fmaxf(logf(pc), -100.0f)
             - (tistop * fmaxf(logf(pt), -100.0f) +
                (1.0f - tistop) * fmaxf(log1pf(-pt), -100.0f));
    } else if (lane >= 61) {
        // hit cells: subtract their all-cells no-obj contribution
        int a = lane - 61;
        if (iou[a] > 0.5f || a == best) {
            float p = sigf(x[((bi * 3 + a) * CH_ + 4) * GG_ + q]);
            nsub = -fmaxf(log1pf(-p), -100.0f);
        }
    }

    for (int off = 32; off; off >>= 1) {
        s512  += __shfl_xor(s512, off);
        cls_s += __shfl_xor(cls_s, off);
        nsub  += __shfl_xor(nsub, off);
    }
    if (lane == 0) {
        int slot = n & 7;
        float hitc = 0.0f;
        #pragma unroll
        for (int a = 0; a < 3; ++a)
            if (iou[a] > 0.5f || a == best) hitc += 1.0f;
        atomicAdd(&ws[64 + slot], (double)s512);
        if (is_top) {
            atomicAdd(&ws[72 + slot],  (double)cls_s);
            atomicAdd(&ws[104 + slot], (double)NTOP_);
        } else {
            atomicAdd(&ws[80 + slot],  (double)cls_s);
            atomicAdd(&ws[112 + slot], (double)(CTOT_ - NTOP_));
        }
        atomicAdd(&ws[88 + slot], (double)nsub);
        atomicAdd(&ws[96 + slot], (double)hitc);
    }
}

__global__ __launch_bounds__(64) void yolo_final(const double* __restrict__ ws,
                                                 float* __restrict__ out) {
    const int lane = threadIdx.x;

    // noobj_all: 64 partial slots, full-wave reduce
    double nb = ws[lane];
    for (int off = 32; off; off >>= 1) nb += __shfl_xor(nb, off);

    // 7 groups of 8 slots at ws[64..119]
    double gv = (lane < 56) ? ws[64 + lane] : 0.0;
    for (int off = 4; off; off >>= 1) gv += __shfl_xor(gv, off); // per-8 sums

    double s512 = __shfl(gv, 0);
    double itm  = __shfl(gv, 8);
    double ibm  = __shfl(gv, 16);
    double nsub = __shfl(gv, 24);
    double hitc = __shfl(gv, 32);
    double itmc = __shfl(gv, 40);
    double ibmc = __shfl(gv, 48);

    if (lane == 0) {
        double nob  = nb - nsub;
        double nobc = (double)PTOT_ - hitc;
        double loss = s512 / 512.0
                    + 10.0 * ((nobc > 0.0) ? nob / fmax(nobc, 1.0) : 0.0)
                    + ((itmc > 0.0) ? itm / fmax(itmc, 1.0) : 0.0)
                    + ((ibmc > 0.0) ? ibm / fmax(ibmc, 1.0) : 0.0);
        out[PTOT_ * CH_] = (float)loss;
    }
}

extern "C" void kernel_launch(void* const* d_in, const int* in_sizes, int n_in,
                              void* d_out, int out_size, void* d_ws, size_t ws_size,
                              hipStream_t stream) {
    const float* x       = (const float*)d_in[0];
    const float* target  = (const float*)d_in[1];
    const float* anchors = (const float*)d_in[2];
    float*  out = (float*)d_out;
    double* ws  = (double*)d_ws;

    // ws is poisoned once and never re-poisoned: zero it ourselves every call.
    hipMemsetAsync(d_ws, 0, 120 * sizeof(double), stream);

    yolo_main <<<dim3(PTOT_ / 64), dim3(256), 0, stream>>>(x, anchors, out, ws);
    yolo_tgt  <<<dim3(NTGT_),      dim3(64),  0, stream>>>(x, target, anchors, ws);
    yolo_final<<<dim3(1),          dim3(64),  0, stream>>>(ws, out);
}

// Round 3
// 51.457 us; speedup vs baseline: 1.7812x; 1.0861x over previous
//
#include <hip/hip_runtime.h>

// Problem constants
#define G_      52
#define GG_     2704          // G*G
#define CH_     88            // 5+1+C
#define NTOP_   53
#define CTOT_   82
#define PTOT_   259584        // B*A*G*G = 32*3*2704
#define NTGT_   512
#define QT_     128           // positions per tile
#define NB_     2028          // PTOT / QT
#define XQ_     253           // NB/8
#define XR_     4             // NB%8

typedef float f32x4 __attribute__((ext_vector_type(4)));

__device__ __forceinline__ float sigf(float v) {
    return 1.0f / (1.0f + __expf(-v));
}

// Swizzled LDS float index, logical layout [88][QT_].
// XOR c bits 2..4 into pos bits 2..4: b128 stays 16B-aligned, transpose
// reads spread ~8 banks (~2.75-way, near-free).
__device__ __forceinline__ int lidx(int c, int pos) {
    return c * QT_ + (pos ^ (((c >> 2) & 7) << 2));
}

// ws layout (doubles):
//  [0..63]    noobj_all partials (yolo_main)
//  [64..71]   s512  [72..79] itm  [80..87] ibm
//  [88..95]   nsub  [96..103] hitc  [104..111] itmc  [112..119] ibmc

__global__ __launch_bounds__(256) void yolo_main(const float* __restrict__ x,
                                                 const float* __restrict__ anchors,
                                                 float* __restrict__ out,
                                                 double* __restrict__ ws) {
    __shared__ float lds[CH_ * QT_];
    const int tid = threadIdx.x;

    // Bijective XCD-chunked swizzle: each XCD gets a contiguous block range
    // so per-channel strided reads form long sequential streams per L2.
    const int orig = blockIdx.x;
    const int xcd  = orig & 7;
    const int lin  = orig >> 3;
    const int bid  = (xcd < XR_ ? xcd * (XQ_ + 1)
                                : XR_ * (XQ_ + 1) + (xcd - XR_) * XQ_) + lin;

    const int pbase = bid * QT_;

    float noobj = 0.0f;

    // read + transform: 88 ch x 128 pos; 8 channel-rows per iter,
    // half-wave (32 lanes) per channel -> 512B contiguous per channel.
    #pragma unroll
    for (int i = 0; i < 11; ++i) {
        int c   = i * 8 + (tid >> 5);      // 0..87 exactly
        int pos = (tid & 31) * 4;
        int p   = pbase + pos;
        int ba  = p / GG_;                 // GG%4==0 -> f4 never crosses ba
        int q   = p - ba * GG_;
        f32x4 v = *(const f32x4*)(x + (ba * CH_ + c) * GG_ + q);
        f32x4 tv;
        if (c >= 4) {
            #pragma unroll
            for (int k = 0; k < 4; ++k) tv[k] = sigf(v[k]);
            if (c == 4) {
                #pragma unroll
                for (int k = 0; k < 4; ++k)
                    noobj -= fmaxf(log1pf(-tv[k]), -100.0f);
            }
        } else if (c == 0) {
            int gx = q % G_;               // q,G mult of 4 -> gx+3 <= 51
            #pragma unroll
            for (int k = 0; k < 4; ++k)
                tv[k] = ((float)(gx + k) + sigf(v[k])) * 8.0f;
        } else if (c == 1) {
            int gy = q / G_;               // constant across the 4
            #pragma unroll
            for (int k = 0; k < 4; ++k)
                tv[k] = ((float)gy + sigf(v[k])) * 8.0f;
        } else {                           // c==2 or c==3
            int a = ba - (ba / 3) * 3;
            float anc = anchors[2 * a + (c - 2)];
            #pragma unroll
            for (int k = 0; k < 4; ++k)
                tv[k] = anc * __expf(v[k]) * 416.0f;
        }
        *(f32x4*)(lds + lidx(c, pos)) = tv;
    }

    // c==4 occurs only for i==0, tid in [128,160) -> wave 2 holds all partials
    if ((tid >> 6) == 2) {
        for (int off = 32; off; off >>= 1)
            noobj += __shfl_xor(noobj, off);
        if (tid == 128)
            atomicAdd(&ws[bid & 63], (double)noobj);
    }
    __syncthreads();

    // write: 128*88 = 11264 floats = 2816 float4s, contiguous; NT stores
    const int ob = pbase * CH_;
    #pragma unroll
    for (int i = 0; i < 11; ++i) {
        int f4  = i * 256 + tid;           // < 2816
        int pos = f4 / 22;
        int c4  = f4 - pos * 22;
        int bse = (c4 * 4) * QT_ + (pos ^ ((c4 & 7) << 2));
        f32x4 o;
        #pragma unroll
        for (int k = 0; k < 4; ++k)
            o[k] = lds[bse + k * QT_];     // same swizzle for k=0..3
        __builtin_nontemporal_store(o, (f32x4*)(out + ob + f4 * 4));
    }
}

// One 64-lane wave per target: class-BCE channels one-per-lane,
// box/conf/istop/noobj-sub terms on lanes 56..63.
__global__ __launch_bounds__(64) void yolo_tgt(const float* __restrict__ x,
                                               const float* __restrict__ tgt,
                                               const float* __restrict__ anchors,
                                               double* __restrict__ ws) {
    const int n    = blockIdx.x;
    const int lane = threadIdx.x;
    const float* t = tgt + n * CH_;

    float a_w[3], a_h[3];
    #pragma unroll
    for (int a = 0; a < 3; ++a) { a_w[a] = anchors[2*a]; a_h[a] = anchors[2*a+1]; }

    int   bi  = (int)t[0];
    float tcx = t[1] * (float)G_;
    float tcy = t[2] * (float)G_;
    float tw  = t[3], th = t[4], tistop = t[5];
    int   ci  = (int)tcx;
    int   cj  = (int)tcy;
    int   q   = cj * G_ + ci;

    float iou[3];
    int best = 0;
    float best_iou = -1.0f;
    #pragma unroll
    for (int a = 0; a < 3; ++a) {
        float inter = fminf(a_w[a], tw) * fminf(a_h[a], th);
        float uni   = tw * th + a_w[a] * a_h[a] - inter + 1e-16f;
        iou[a] = inter / uni;
        if (iou[a] > best_iou) { best_iou = iou[a]; best = a; }
    }

    const float* cell = x + (bi * 3 + best) * CH_ * GG_ + q;  // ch stride GG_
    bool is_top = tistop > 0.5f;
    int  c0 = is_top ? 0 : NTOP_;
    int  nc = is_top ? NTOP_ : (CTOT_ - NTOP_);

    float cls_s = 0.0f, s512 = 0.0f, nsub = 0.0f;
    if (lane < nc) {
        int c = c0 + lane;
        float p  = sigf(cell[(6 + c) * GG_]);
        float tv = t[6 + c];
        cls_s = -(tv * fmaxf(logf(p), -100.0f) +
                  (1.0f - tv) * fmaxf(log1pf(-p), -100.0f));
    } else if (lane >= 56 && lane < 60) {
        int k = lane - 56;
        float v = cell[k * GG_];
        float tv;
        if      (k == 0) tv = tcx - floorf(tcx);
        else if (k == 1) tv = tcy - floorf(tcy);
        else if (k == 2) tv = logf(tw / a_w[best] + 1e-16f);
        else             tv = logf(th / a_h[best] + 1e-16f);
        float d = (k < 2 ? sigf(v) : v) - tv;
        s512 = d * d;
    } else if (lane == 60) {
        float pc = sigf(cell[4 * GG_]);
        float pt = sigf(cell[5 * GG_]);
        s512 = -fmaxf(logf(pc), -100.0f)
             - (tistop * fmaxf(logf(pt), -100.0f) +
                (1.0f - tistop) * fmaxf(log1pf(-pt), -100.0f));
    } else if (lane >= 61) {
        int a = lane - 61;
        if (iou[a] > 0.5f || a == best) {
            float p = sigf(x[((bi * 3 + a) * CH_ + 4) * GG_ + q]);
            nsub = -fmaxf(log1pf(-p), -100.0f);
        }
    }

    for (int off = 32; off; off >>= 1) {
        s512  += __shfl_xor(s512, off);
        cls_s += __shfl_xor(cls_s, off);
        nsub  += __shfl_xor(nsub, off);
    }
    if (lane == 0) {
        int slot = n & 7;
        float hitc = 0.0f;
        #pragma unroll
        for (int a = 0; a < 3; ++a)
            if (iou[a] > 0.5f || a == best) hitc += 1.0f;
        atomicAdd(&ws[64 + slot], (double)s512);
        if (is_top) {
            atomicAdd(&ws[72 + slot],  (double)cls_s);
            atomicAdd(&ws[104 + slot], (double)NTOP_);
        } else {
            atomicAdd(&ws[80 + slot],  (double)cls_s);
            atomicAdd(&ws[112 + slot], (double)(CTOT_ - NTOP_));
        }
        atomicAdd(&ws[88 + slot], (double)nsub);
        atomicAdd(&ws[96 + slot], (double)hitc);
    }
}

__global__ __launch_bounds__(64) void yolo_final(const double* __restrict__ ws,
                                                 float* __restrict__ out) {
    const int lane = threadIdx.x;

    double nb = ws[lane];
    for (int off = 32; off; off >>= 1) nb += __shfl_xor(nb, off);

    double gv = (lane < 56) ? ws[64 + lane] : 0.0;
    for (int off = 4; off; off >>= 1) gv += __shfl_xor(gv, off);

    double s512 = __shfl(gv, 0);
    double itm  = __shfl(gv, 8);
    double ibm  = __shfl(gv, 16);
    double nsub = __shfl(gv, 24);
    double hitc = __shfl(gv, 32);
    double itmc = __shfl(gv, 40);
    double ibmc = __shfl(gv, 48);

    if (lane == 0) {
        double nob  = nb - nsub;
        double nobc = (double)PTOT_ - hitc;
        double loss = s512 / 512.0
                    + 10.0 * ((nobc > 0.0) ? nob / fmax(nobc, 1.0) : 0.0)
                    + ((itmc > 0.0) ? itm / fmax(itmc, 1.0) : 0.0)
                    + ((ibmc > 0.0) ? ibm / fmax(ibmc, 1.0) : 0.0);
        out[PTOT_ * CH_] = (float)loss;
    }
}

extern "C" void kernel_launch(void* const* d_in, const int* in_sizes, int n_in,
                              void* d_out, int out_size, void* d_ws, size_t ws_size,
                              hipStream_t stream) {
    const float* x       = (const float*)d_in[0];
    const float* target  = (const float*)d_in[1];
    const float* anchors = (const float*)d_in[2];
    float*  out = (float*)d_out;
    double* ws  = (double*)d_ws;

    hipMemsetAsync(d_ws, 0, 120 * sizeof(double), stream);

    yolo_main <<<dim3(NB_),   dim3(256), 0, stream>>>(x, anchors, out, ws);
    yolo_tgt  <<<dim3(NTGT_), dim3(64),  0, stream>>>(x, target, anchors, ws);
    yolo_final<<<dim3(1),     dim3(64),  0, stream>>>(ws, out);
}